// Round 6
// baseline (275.867 us; speedup 1.0000x reference)
//
#include <hip/hip_runtime.h>
#include <hip/hip_bf16.h>
#include <math.h>

// TopK router: logits = x @ gate_w^T, softmax, top-2, renormalize.
// M=32768 tokens, K=4096, E=64 experts.
// Outputs (concat, harness reads whole buffer as float32):
//   d_out[0 .. 2M)  : top-2 weights (descending)
//   d_out[2M .. 4M) : top-2 expert indices, stored as float values
//
// R6: light waves. Block = 32 tokens, 4 waves = 2-way M-split x 2-way
// K-split(2048). Per wave per k=32 step: 8 packed-B loads (L2-hot) + 2 A
// loads (1-step named double-buffer) + 16 MFMA (hh+hl+lh+ll). ~100 VGPR ->
// real 4 waves/SIMD, deep in-flight load queue, HBM-bound by design.
// Packed bf16 hi/lo B via prep_b (R5), TAU=1e-4 + parallel fp64 refine (R5).

typedef __attribute__((ext_vector_type(8))) short short8;
typedef __attribute__((ext_vector_type(4))) float f32x4;

#define TPB 32      // tokens per block
#define TAU 1e-4f   // near-tie refine threshold (4-term logit noise ~1e-6)
#define LROW 68     // padded logits stride (floats)

__device__ __forceinline__ void cvt8(const float4* v, short8* hi, short8* lo) {
    const float* f = reinterpret_cast<const float*>(v);
#pragma unroll
    for (int j = 0; j < 8; ++j) {
        __hip_bfloat16 h = __float2bfloat16(f[j]);
        float r = f[j] - __bfloat162float(h);
        __hip_bfloat16 l = __float2bfloat16(r);
        (*hi)[j] = (short)*reinterpret_cast<unsigned short*>(&h);
        (*lo)[j] = (short)*reinterpret_cast<unsigned short*>(&l);
    }
}

// Pack gw (64x4096 f32) into MFMA-fragment-ordered bf16 hi/lo arrays:
// entry (nt*8192 + w*64 + ln) holds 8 bf16 of row nt*16+(ln&15),
// k = w*32 + (ln>>4)*8 .. +8.  A wave's 64 lanes read 1KB contiguous.
__global__ void prep_b(const float* __restrict__ gw,
                       short8* __restrict__ bh, short8* __restrict__ bl) {
    const int tid = blockIdx.x * 256 + threadIdx.x;   // 0..32767
    const int ln  = tid & 63;
    const int w   = (tid >> 6) & 127;
    const int nt  = tid >> 13;
    const int row = nt * 16 + (ln & 15);
    const int k   = w * 32 + ((ln >> 4) << 3);
    float4 v[2];
    v[0] = *reinterpret_cast<const float4*>(gw + (long)row * 4096 + k);
    v[1] = *reinterpret_cast<const float4*>(gw + (long)row * 4096 + k + 4);
    short8 h, l;
    cvt8(v, &h, &l);
    bh[tid] = h;
    bl[tid] = l;
}

#define WSTEP(ACUR, APRE, PREOFF, WIDX) do {                                  \
    const long bi = bidx0 + (long)(WIDX) * 64;                                \
    short8 bh0 = bhp[bi], bh1 = bhp[bi + 8192],                               \
           bh2 = bhp[bi + 16384], bh3 = bhp[bi + 24576];                      \
    short8 bl0 = blp[bi], bl1 = blp[bi + 8192],                               \
           bl2 = blp[bi + 16384], bl3 = blp[bi + 24576];                      \
    (APRE)[0] = *reinterpret_cast<const float4*>(pA + (PREOFF));              \
    (APRE)[1] = *reinterpret_cast<const float4*>(pA + (PREOFF) + 4);          \
    __builtin_amdgcn_sched_barrier(0);                                        \
    short8 ah, al;                                                            \
    cvt8((ACUR), &ah, &al);                                                   \
    acc[0] = __builtin_amdgcn_mfma_f32_16x16x32_bf16(ah, bh0, acc[0], 0, 0, 0); \
    acc[0] = __builtin_amdgcn_mfma_f32_16x16x32_bf16(ah, bl0, acc[0], 0, 0, 0); \
    acc[0] = __builtin_amdgcn_mfma_f32_16x16x32_bf16(al, bh0, acc[0], 0, 0, 0); \
    acc[0] = __builtin_amdgcn_mfma_f32_16x16x32_bf16(al, bl0, acc[0], 0, 0, 0); \
    acc[1] = __builtin_amdgcn_mfma_f32_16x16x32_bf16(ah, bh1, acc[1], 0, 0, 0); \
    acc[1] = __builtin_amdgcn_mfma_f32_16x16x32_bf16(ah, bl1, acc[1], 0, 0, 0); \
    acc[1] = __builtin_amdgcn_mfma_f32_16x16x32_bf16(al, bh1, acc[1], 0, 0, 0); \
    acc[1] = __builtin_amdgcn_mfma_f32_16x16x32_bf16(al, bl1, acc[1], 0, 0, 0); \
    acc[2] = __builtin_amdgcn_mfma_f32_16x16x32_bf16(ah, bh2, acc[2], 0, 0, 0); \
    acc[2] = __builtin_amdgcn_mfma_f32_16x16x32_bf16(ah, bl2, acc[2], 0, 0, 0); \
    acc[2] = __builtin_amdgcn_mfma_f32_16x16x32_bf16(al, bh2, acc[2], 0, 0, 0); \
    acc[2] = __builtin_amdgcn_mfma_f32_16x16x32_bf16(al, bl2, acc[2], 0, 0, 0); \
    acc[3] = __builtin_amdgcn_mfma_f32_16x16x32_bf16(ah, bh3, acc[3], 0, 0, 0); \
    acc[3] = __builtin_amdgcn_mfma_f32_16x16x32_bf16(ah, bl3, acc[3], 0, 0, 0); \
    acc[3] = __builtin_amdgcn_mfma_f32_16x16x32_bf16(al, bh3, acc[3], 0, 0, 0); \
    acc[3] = __builtin_amdgcn_mfma_f32_16x16x32_bf16(al, bl3, acc[3], 0, 0, 0); \
} while (0)

__global__ __launch_bounds__(256, 4)
void router_mfma_topk(const float* __restrict__ x,
                      const short8* __restrict__ bhp,
                      const short8* __restrict__ blp,
                      const float* __restrict__ gw,
                      float* __restrict__ out,
                      int M, int K) {
    __shared__ float Lp[2 * TPB * LROW];    // per-K-half partial logits
    __shared__ int flags[TPB];
    __shared__ double Ld4[4][64];

    const int t  = threadIdx.x;
    const int wv = t >> 6;
    const int km = wv & 1;                  // K-half (2048)
    const int mm = wv >> 1;                 // m-tile (16 tokens)
    const int ln = t & 63;
    const int fr = ln & 15;
    const int q  = ln >> 4;
    const long tok0 = (long)blockIdx.x * TPB;

    const float* pA = x + (tok0 + mm * 16 + fr) * (long)K + km * 2048 + q * 8;
    const long bidx0 = (long)(km * 64) * 64 + ln;   // + nt*8192 + i*64

    f32x4 acc[4];
#pragma unroll
    for (int nt = 0; nt < 4; ++nt) acc[nt] = (f32x4){0.f, 0.f, 0.f, 0.f};

    float4 a0[2], a1[2];
    a0[0] = *reinterpret_cast<const float4*>(pA);
    a0[1] = *reinterpret_cast<const float4*>(pA + 4);

    for (int i = 0; i < 64; i += 2) {
        // window i: compute a0, prefetch a1
        WSTEP(a0, a1, (i + 1) * 32, i);
        // window i+1: compute a1, prefetch a0 (guard tail)
        const int pre = (i + 2 < 64) ? (i + 2) * 32 : 0;
        WSTEP(a1, a0, pre, i + 1);
    }

    // ---- dump partials: C/D layout col=lane&15, row=q*4+r ----
    float* myLp = Lp + km * (TPB * LROW);
#pragma unroll
    for (int nt = 0; nt < 4; ++nt)
#pragma unroll
        for (int r = 0; r < 4; ++r)
            myLp[(mm * 16 + q * 4 + r) * LROW + nt * 16 + fr] = acc[nt][r];
    __syncthreads();

    // ---- reduce the two K-halves ----
    for (int i = t; i < TPB * LROW; i += 256)
        Lp[i] += Lp[TPB * LROW + i];
    __syncthreads();

    // ---- top-3 scan + provisional output + near-tie flag ----
    if (t < TPB) {
        const float* row = Lp + (long)t * LROW;
        float m1 = -INFINITY, m2 = -INFINITY, m3 = -INFINITY;
        int i1 = 0, i2 = 0;
#pragma unroll 8
        for (int e = 0; e < 64; ++e) {
            const float v = row[e];
            if (v > m1)      { m3 = m2; m2 = m1; i2 = i1; m1 = v; i1 = e; }
            else if (v > m2) { m3 = m2; m2 = v; i2 = e; }
            else if (v > m3) { m3 = v; }
        }
        const float e2 = expf(m2 - m1);
        const float s  = 1.0f + e2;

        const long g = tok0 + t;
        out[2 * g + 0] = 1.0f / s;
        out[2 * g + 1] = e2 / s;
        float* oi = out + 2 * (long)M;
        oi[2 * g + 0] = (float)i1;
        oi[2 * g + 1] = (float)i2;

        flags[t] = ((m1 - m2) < TAU) | ((m2 - m3) < TAU);
    }
    __syncthreads();

    // ---- fp64 refine, 256 threads cooperate (wave=K-quarter, lane=expert) ----
    for (int tk = 0; tk < TPB; ++tk) {
        if (flags[tk]) {
            const float* xr = x + (tok0 + tk) * (long)K + wv * 1024;
            const float* gr = gw + (long)ln * (long)K + wv * 1024;
            double s0 = 0.0, s1 = 0.0, s2 = 0.0, s3 = 0.0;
            for (int k = 0; k < 1024; k += 4) {
                const float4 a = *reinterpret_cast<const float4*>(xr + k);
                const float4 b = *reinterpret_cast<const float4*>(gr + k);
                s0 = fma((double)a.x, (double)b.x, s0);
                s1 = fma((double)a.y, (double)b.y, s1);
                s2 = fma((double)a.z, (double)b.z, s2);
                s3 = fma((double)a.w, (double)b.w, s3);
            }
            Ld4[wv][ln] = (s0 + s1) + (s2 + s3);
            __syncthreads();
            if (t == 0) {
                double m1 = -INFINITY, m2 = -INFINITY;
                int i1 = 0, i2 = 0;
                for (int e = 0; e < 64; ++e) {
                    const double v = Ld4[0][e] + Ld4[1][e] + Ld4[2][e] + Ld4[3][e];
                    if (v > m1)      { m2 = m1; i2 = i1; m1 = v; i1 = e; }
                    else if (v > m2) { m2 = v; i2 = e; }
                }
                const double e2 = exp(m2 - m1);
                const double s  = 1.0 + e2;
                const long g = tok0 + tk;
                out[2 * g + 0] = (float)(1.0 / s);
                out[2 * g + 1] = (float)(e2 / s);
                float* oi = out + 2 * (long)M;
                oi[2 * g + 0] = (float)i1;
                oi[2 * g + 1] = (float)i2;
            }
            __syncthreads();
        }
    }
}

extern "C" void kernel_launch(void* const* d_in, const int* in_sizes, int n_in,
                              void* d_out, int out_size, void* d_ws, size_t ws_size,
                              hipStream_t stream) {
    const float* x  = (const float*)d_in[0];
    const float* gw = (const float*)d_in[1];
    float* out = (float*)d_out;

    const int K = 4096;
    const int M = in_sizes[0] / K;          // 32768 tokens
    const int nblocks = M / TPB;            // 1024

    short8* bh = (short8*)d_ws;
    short8* bl = bh + 32768;
    prep_b<<<128, 256, 0, stream>>>(gw, bh, bl);
    router_mfma_topk<<<nblocks, 256, 0, stream>>>(x, bh, bl, gw, out, M, K);
}